// Round 3
// baseline (565.638 us; speedup 1.0000x reference)
//
#include <hip/hip_runtime.h>
#include <math.h>

#define NROWS 65536
#define NCLS  1000
#define ALPHA 1.0f
#define BETA  1.5f
#define ROWS_PER_BLOCK 4
#define NBLOCKS (NROWS / ROWS_PER_BLOCK)   // 16384

// Block-wide sum over 256 threads (4 waves): wave shuffle + 4-slot LDS.
__device__ __forceinline__ float block_sum256(float x, volatile float* red4) {
#pragma unroll
    for (int off = 32; off > 0; off >>= 1) x += __shfl_xor(x, off);
    if ((threadIdx.x & 63) == 0) red4[threadIdx.x >> 6] = x;
    __syncthreads();
    float r = red4[0] + red4[1] + red4[2] + red4[3];
    __syncthreads();
    return r;
}

__device__ __forceinline__ float sig_scale(float norm) {
    return BETA / (1.0f + __expf(-norm / ALPHA)) - BETA * 0.5f + 1.0f;
}

// One 64-lane wave per row: single HBM pass (250 float4 into registers),
// wave max-reduce, exp-sum reduce, CE + atomics into per-class sums/counts.
// The LAST block (atomic counter) then does the 1000-class finalize:
// losses = sums/counts, standardize (unbiased std), sigmoid scale, sum.
__global__ __launch_bounds__(256) void fused_ce_kernel(
    const float* __restrict__ inp, const int* __restrict__ tgt,
    float* __restrict__ sums, float* __restrict__ counts,
    unsigned int* __restrict__ done, float* __restrict__ out)
{
    const int wave = threadIdx.x >> 6;
    const int lane = threadIdx.x & 63;
    const int row  = blockIdx.x * ROWS_PER_BLOCK + wave;   // always < NROWS

    const float4* rp = reinterpret_cast<const float4*>(inp + (size_t)row * NCLS);

    // 250 float4 chunks per row; lane handles chunks lane + 64*k, k=0..3
    // (k=3 exists only for lane < 58 since 250 = 3*64 + 58).
    float4 v[4];
    const bool has4 = (lane < 58);
#pragma unroll
    for (int k = 0; k < 3; ++k) v[k] = rp[lane + 64 * k];
    v[3] = has4 ? rp[lane + 192]
                : make_float4(-INFINITY, -INFINITY, -INFINITY, -INFINITY);

    // lane-local max, then wave max
    float m = -INFINITY;
#pragma unroll
    for (int k = 0; k < 4; ++k)
        m = fmaxf(m, fmaxf(fmaxf(v[k].x, v[k].y), fmaxf(v[k].z, v[k].w)));
#pragma unroll
    for (int off = 32; off > 0; off >>= 1)
        m = fmaxf(m, __shfl_xor(m, off));

    // exp-sum from registers (exp(-inf - m) == 0, padding harmless)
    float s = 0.f;
#pragma unroll
    for (int k = 0; k < 4; ++k) {
        s += __expf(v[k].x - m);
        s += __expf(v[k].y - m);
        s += __expf(v[k].z - m);
        s += __expf(v[k].w - m);
    }
#pragma unroll
    for (int off = 32; off > 0; off >>= 1)
        s += __shfl_xor(s, off);

    if (lane == 0) {
        const int t = tgt[row];
        const float picked = inp[(size_t)row * NCLS + t];   // L1-hot
        const float ce = m + __logf(s) - picked;
        atomicAdd(&sums[t], ce);
        atomicAdd(&counts[t], 1.0f);
    }

    // ---- last-block-done: the final block performs the finalize ----
    __shared__ unsigned int is_last;
    __shared__ float red4[4];
    __syncthreads();                 // all block atomics issued+drained
    if (threadIdx.x == 0) {
        __threadfence();             // make them visible device-wide
        const unsigned int old = atomicAdd(done, 1u);
        is_last = (old == NBLOCKS - 1) ? 1u : 0u;
    }
    __syncthreads();
    if (!is_last) return;

    // last block: all other blocks' sums/counts are complete & visible.
    const int c = threadIdx.x;                 // 256 threads, 1000 classes
    const bool has3 = (c + 768 < NCLS);
    volatile const float* vs = sums;           // bypass L1, read fresh L2
    volatile const float* vc = counts;
    const float l0 = vs[c      ] / vc[c      ];
    const float l1 = vs[c + 256] / vc[c + 256];
    const float l2 = vs[c + 512] / vc[c + 512];
    const float l3 = has3 ? (vs[c + 768] / vc[c + 768]) : 0.f;

    const float total = block_sum256(l0 + l1 + l2 + l3, red4);
    const float mean  = total * (1.0f / (float)NCLS);

    const float d0 = l0 - mean, d1 = l1 - mean, d2 = l2 - mean;
    const float d3 = has3 ? (l3 - mean) : 0.f;
    const float sqt = block_sum256(d0*d0 + d1*d1 + d2*d2 + d3*d3, red4);
    const float inv_std = 1.0f / sqrtf(sqt / (float)(NCLS - 1));

    float w = l0 * sig_scale(d0 * inv_std)
            + l1 * sig_scale(d1 * inv_std)
            + l2 * sig_scale(d2 * inv_std);
    if (has3) w += l3 * sig_scale(d3 * inv_std);
    const float wsum = block_sum256(w, red4);
    if (c == 0) out[0] = wsum;
}

extern "C" void kernel_launch(void* const* d_in, const int* in_sizes, int n_in,
                              void* d_out, int out_size, void* d_ws, size_t ws_size,
                              hipStream_t stream)
{
    const float* inp = (const float*)d_in[0];
    const int*   tgt = (const int*)d_in[1];
    float* out = (float*)d_out;

    float* sums   = (float*)d_ws;              // [1000]
    float* counts = sums + NCLS;               // [1000]
    unsigned int* done = (unsigned int*)(counts + NCLS);  // [1]

    // ws is poisoned (0xAA) once and never re-poisoned -> zero it each call.
    hipMemsetAsync(d_ws, 0, (2 * NCLS + 1) * sizeof(float), stream);

    fused_ce_kernel<<<NBLOCKS, 256, 0, stream>>>(inp, tgt, sums, counts, done, out);
}

// Round 4
// 54.386 us; speedup vs baseline: 10.4005x; 10.4005x over previous
//
#include <hip/hip_runtime.h>
#include <math.h>

#define NROWS 65536
#define NCLS  1000
#define ALPHA 1.0f
#define BETA  1.5f
#define NBLOCKS 2048                         // 8 blocks/CU on 256 CUs
#define WAVES_TOTAL (NBLOCKS * 4)            // 8192 waves
#define ROWS_PER_WAVE (NROWS / WAVES_TOTAL)  // 8

// Block-wide sum over 256 threads (4 waves): wave shuffle + 4-slot LDS.
__device__ __forceinline__ float block_sum256(float x, volatile float* red4) {
#pragma unroll
    for (int off = 32; off > 0; off >>= 1) x += __shfl_xor(x, off);
    if ((threadIdx.x & 63) == 0) red4[threadIdx.x >> 6] = x;
    __syncthreads();
    float r = red4[0] + red4[1] + red4[2] + red4[3];
    __syncthreads();
    return r;
}

__device__ __forceinline__ float sig_scale(float norm) {
    return BETA / (1.0f + __expf(-norm / ALPHA)) - BETA * 0.5f + 1.0f;
}

// One 64-lane wave per row, 8 rows per wave (persistent grid).
// Per row: single HBM pass (250 float4 into registers), wave max-reduce,
// exp-sum reduce, CE + global atomics into per-class sums/counts.
// NO device-scope fences anywhere (R3 lesson: fence-per-block = 15x regression).
__global__ __launch_bounds__(256) void ce_rows_kernel(
    const float* __restrict__ inp, const int* __restrict__ tgt,
    float* __restrict__ sums, float* __restrict__ counts)
{
    const int lane  = threadIdx.x & 63;
    const int gwave = blockIdx.x * 4 + (threadIdx.x >> 6);
    const bool has4 = (lane < 58);   // 250 = 3*64 + 58 float4 chunks per row

    for (int i = 0; i < ROWS_PER_WAVE; ++i) {
        const int row = gwave + i * WAVES_TOTAL;   // device-wide contiguous window
        const float4* rp = reinterpret_cast<const float4*>(inp + (size_t)row * NCLS);

        float4 v[4];
#pragma unroll
        for (int k = 0; k < 3; ++k) v[k] = rp[lane + 64 * k];
        v[3] = has4 ? rp[lane + 192]
                    : make_float4(-INFINITY, -INFINITY, -INFINITY, -INFINITY);

        // lane-local max, then wave max
        float m = -INFINITY;
#pragma unroll
        for (int k = 0; k < 4; ++k)
            m = fmaxf(m, fmaxf(fmaxf(v[k].x, v[k].y), fmaxf(v[k].z, v[k].w)));
#pragma unroll
        for (int off = 32; off > 0; off >>= 1)
            m = fmaxf(m, __shfl_xor(m, off));

        // exp-sum from registers (exp(-inf - m) == 0, padding harmless)
        float s = 0.f;
#pragma unroll
        for (int k = 0; k < 4; ++k) {
            s += __expf(v[k].x - m);
            s += __expf(v[k].y - m);
            s += __expf(v[k].z - m);
            s += __expf(v[k].w - m);
        }
#pragma unroll
        for (int off = 32; off > 0; off >>= 1)
            s += __shfl_xor(s, off);

        if (lane == 0) {
            const int t = tgt[row];
            const float picked = inp[(size_t)row * NCLS + t];   // L1-hot
            const float ce = m + __logf(s) - picked;
            atomicAdd(&sums[t], ce);
            atomicAdd(&counts[t], 1.0f);
        }
    }
}

// Single 256-thread block: losses = sums/counts; mean; unbiased std;
// sigmoid scale; weighted sum -> out[0]. Runs as a separate dispatch, so
// kernel-boundary coherence makes the atomics' results visible (R2-proven).
__global__ __launch_bounds__(256) void finalize_kernel(
    const float* __restrict__ sums, const float* __restrict__ counts,
    float* __restrict__ out)
{
    __shared__ float red4[4];
    const int c = threadIdx.x;                 // 256 threads, 1000 classes
    const bool has3 = (c + 768 < NCLS);

    const float l0 = sums[c      ] / counts[c      ];
    const float l1 = sums[c + 256] / counts[c + 256];
    const float l2 = sums[c + 512] / counts[c + 512];
    const float l3 = has3 ? (sums[c + 768] / counts[c + 768]) : 0.f;

    const float total = block_sum256(l0 + l1 + l2 + l3, red4);
    const float mean  = total * (1.0f / (float)NCLS);

    const float d0 = l0 - mean, d1 = l1 - mean, d2 = l2 - mean;
    const float d3 = has3 ? (l3 - mean) : 0.f;
    const float sqt = block_sum256(d0*d0 + d1*d1 + d2*d2 + d3*d3, red4);
    const float inv_std = 1.0f / sqrtf(sqt / (float)(NCLS - 1));

    float w = l0 * sig_scale(d0 * inv_std)
            + l1 * sig_scale(d1 * inv_std)
            + l2 * sig_scale(d2 * inv_std);
    if (has3) w += l3 * sig_scale(d3 * inv_std);
    const float wsum = block_sum256(w, red4);
    if (c == 0) out[0] = wsum;
}

extern "C" void kernel_launch(void* const* d_in, const int* in_sizes, int n_in,
                              void* d_out, int out_size, void* d_ws, size_t ws_size,
                              hipStream_t stream)
{
    const float* inp = (const float*)d_in[0];
    const int*   tgt = (const int*)d_in[1];
    float* out = (float*)d_out;

    float* sums   = (float*)d_ws;              // [1000]
    float* counts = sums + NCLS;               // [1000]

    // ws is poisoned (0xAA) once and never re-poisoned -> zero it each call.
    hipMemsetAsync(d_ws, 0, 2 * NCLS * sizeof(float), stream);

    ce_rows_kernel<<<NBLOCKS, 256, 0, stream>>>(inp, tgt, sums, counts);
    finalize_kernel<<<1, 256, 0, stream>>>(sums, counts, out);
}